// Round 1
// baseline (1080.234 us; speedup 1.0000x reference)
//
#include <hip/hip_runtime.h>
#include <cmath>

#define BB 2
#define SS 2048
#define DD 1024
#define HH 16
#define HDD 64
#define MM (BB * SS)

static constexpr float EPS_F = 1e-5f;

// ---------------------------------------------------------------------------
// RoPE cos/sin table: S x 32 entries, computed in double to match numpy.
// ---------------------------------------------------------------------------
__global__ __launch_bounds__(256) void k_rope_table(float* __restrict__ cosT,
                                                    float* __restrict__ sinT) {
    int idx = blockIdx.x * 256 + threadIdx.x;  // 0 .. S*32-1
    int s = idx >> 5, j = idx & 31;
    double inv = pow(10000.0, -(double)(2 * j) / 64.0);
    double ang = (double)s * inv;
    cosT[idx] = (float)cos(ang);
    sinT[idx] = (float)sin(ang);
}

// ---------------------------------------------------------------------------
// QKV GEMM: C = x @ W{q,k,v}, RoPE fused for Q,K. Output layout (B,H,S,HD).
// 128x128 tile, BK=16, 256 threads, 8x8 per thread (2x2 quadrants of 4x4).
// ---------------------------------------------------------------------------
__global__ __launch_bounds__(256) void k_qkv(const float* __restrict__ x,
        const float* __restrict__ Wq, const float* __restrict__ Wk,
        const float* __restrict__ Wv,
        const float* __restrict__ cosT, const float* __restrict__ sinT,
        float* __restrict__ Qg, float* __restrict__ Kg, float* __restrict__ Vg) {
    const int z = blockIdx.z;
    const float* __restrict__ Wm = (z == 0) ? Wq : (z == 1) ? Wk : Wv;
    float* __restrict__ dst = (z == 0) ? Qg : (z == 1) ? Kg : Vg;
    const int m0 = blockIdx.x * 128;
    const int n0 = blockIdx.y * 128;
    __shared__ float AsT[16][128];
    __shared__ float Bs[16][128];
    const int tid = threadIdx.x;
    const int ty = tid >> 4, tx = tid & 15;
    const int ar = tid >> 1, akc = (tid & 1) * 8;
    const int bk = tid >> 4, bc = (tid & 15) * 8;
    float acc[2][2][4][4] = {};
    for (int k0 = 0; k0 < DD; k0 += 16) {
        float4 a0 = *(const float4*)&x[(m0 + ar) * DD + k0 + akc];
        float4 a1 = *(const float4*)&x[(m0 + ar) * DD + k0 + akc + 4];
        float4 b0 = *(const float4*)&Wm[(k0 + bk) * DD + n0 + bc];
        float4 b1 = *(const float4*)&Wm[(k0 + bk) * DD + n0 + bc + 4];
        __syncthreads();
        AsT[akc + 0][ar] = a0.x; AsT[akc + 1][ar] = a0.y;
        AsT[akc + 2][ar] = a0.z; AsT[akc + 3][ar] = a0.w;
        AsT[akc + 4][ar] = a1.x; AsT[akc + 5][ar] = a1.y;
        AsT[akc + 6][ar] = a1.z; AsT[akc + 7][ar] = a1.w;
        *(float4*)&Bs[bk][bc] = b0;
        *(float4*)&Bs[bk][bc + 4] = b1;
        __syncthreads();
#pragma unroll
        for (int kk = 0; kk < 16; ++kk) {
            float aa[2][4], bb2[2][4];
            *(float4*)aa[0] = *(const float4*)&AsT[kk][4 * ty];
            *(float4*)aa[1] = *(const float4*)&AsT[kk][64 + 4 * ty];
            *(float4*)bb2[0] = *(const float4*)&Bs[kk][4 * tx];
            *(float4*)bb2[1] = *(const float4*)&Bs[kk][64 + 4 * tx];
#pragma unroll
            for (int qi = 0; qi < 2; ++qi)
#pragma unroll
                for (int qj = 0; qj < 2; ++qj)
#pragma unroll
                    for (int i = 0; i < 4; ++i)
#pragma unroll
                        for (int j = 0; j < 4; ++j)
                            acc[qi][qj][i][j] =
                                fmaf(aa[qi][i], bb2[qj][j], acc[qi][qj][i][j]);
        }
    }
    // Epilogue: RoPE (for Q,K) + store in (B,H,S,HD)
#pragma unroll
    for (int qi = 0; qi < 2; ++qi) {
#pragma unroll
        for (int i = 0; i < 4; ++i) {
            int mg = m0 + qi * 64 + 4 * ty + i;
            int bidx = mg >> 11;           // / S
            int srow = mg & (SS - 1);
#pragma unroll
            for (int qj = 0; qj < 2; ++qj) {
                int ng = n0 + qj * 64 + 4 * tx;
                int h = ng >> 6;
                int hd0 = ng & 63;         // multiple of 4
                float v0 = acc[qi][qj][i][0], v1 = acc[qi][qj][i][1];
                float v2 = acc[qi][qj][i][2], v3 = acc[qi][qj][i][3];
                if (z < 2) {
                    int p0 = hd0 >> 1;     // pair indices p0, p0+1
                    float c0 = cosT[srow * 32 + p0], s0 = sinT[srow * 32 + p0];
                    float c1 = cosT[srow * 32 + p0 + 1], s1 = sinT[srow * 32 + p0 + 1];
                    float e0 = v0 * c0 - v1 * s0;
                    float o0 = v0 * s0 + v1 * c0;
                    float e1 = v2 * c1 - v3 * s1;
                    float o1 = v2 * s1 + v3 * c1;
                    v0 = e0; v1 = o0; v2 = e1; v3 = o1;
                }
                float4 st = make_float4(v0, v1, v2, v3);
                *(float4*)&dst[(((size_t)bidx * HH + h) * SS + srow) * 64 + hd0] = st;
            }
        }
    }
}

// ---------------------------------------------------------------------------
// Flash-style Yat attention. One block = (b,h) x 64-row Q tile.
// scores = scale * qk^2 / (|q-k|^2 + eps), causal, online softmax, PV.
// K and V time-share one LDS buffer to stay under 64KB static LDS.
// ---------------------------------------------------------------------------
__global__ __launch_bounds__(256) void k_attn(const float* __restrict__ Qg,
        const float* __restrict__ Kg, const float* __restrict__ Vg,
        const float* __restrict__ alpha, float* __restrict__ AO) {
    const int qt = 31 - blockIdx.x;    // longest blocks first
    const int bh = blockIdx.y;
    const float* __restrict__ Qh = Qg + (size_t)bh * SS * 64;
    const float* __restrict__ Kh = Kg + (size_t)bh * SS * 64;
    const float* __restrict__ Vh = Vg + (size_t)bh * SS * 64;
    __shared__ float QsT[64][64];      // [d][r]
    __shared__ float KV[64][64];       // KsT [d][c], then Vs [c][d]
    __shared__ float Ps[64][68];       // scores/probs, padded
    __shared__ float qn[64], kn[64], mrow[64], lrow[64], sfrow[64];
    const int tid = threadIdx.x;
    const int ty = tid >> 4, tx = tid & 15;
    const float scl = powf(8.0f / logf(65.0f), alpha[0]);

    // Stage Q transposed + row norms (RoPE preserves norms; these equal qn).
    {
        int r = tid >> 2, d0 = (tid & 3) * 16;
        const float* src = &Qh[(qt * 64 + r) * 64 + d0];
        float pn = 0.f;
#pragma unroll
        for (int u = 0; u < 4; ++u) {
            float4 v = *(const float4*)(src + 4 * u);
            QsT[d0 + 4 * u + 0][r] = v.x; QsT[d0 + 4 * u + 1][r] = v.y;
            QsT[d0 + 4 * u + 2][r] = v.z; QsT[d0 + 4 * u + 3][r] = v.w;
            pn += v.x * v.x + v.y * v.y + v.z * v.z + v.w * v.w;
        }
        pn += __shfl_xor(pn, 1);
        pn += __shfl_xor(pn, 2);
        if ((tid & 3) == 0) qn[r] = pn;
        if (tid < 64) { mrow[tid] = -INFINITY; lrow[tid] = 0.f; }
    }
    float accO[4][4] = {};
    for (int kt = 0; kt <= qt; ++kt) {
        __syncthreads();   // protect KV overwrite vs prev-iter PV reads
        {   // stage K transposed + kn
            int c = tid >> 2, d0 = (tid & 3) * 16;
            const float* src = &Kh[(kt * 64 + c) * 64 + d0];
            float pn = 0.f;
#pragma unroll
            for (int u = 0; u < 4; ++u) {
                float4 v = *(const float4*)(src + 4 * u);
                KV[d0 + 4 * u + 0][c] = v.x; KV[d0 + 4 * u + 1][c] = v.y;
                KV[d0 + 4 * u + 2][c] = v.z; KV[d0 + 4 * u + 3][c] = v.w;
                pn += v.x * v.x + v.y * v.y + v.z * v.z + v.w * v.w;
            }
            pn += __shfl_xor(pn, 1);
            pn += __shfl_xor(pn, 2);
            if ((tid & 3) == 0) kn[c] = pn;
        }
        __syncthreads();
        // QK^T: each thread 4x4
        float qk[4][4] = {};
#pragma unroll
        for (int kk = 0; kk < 64; ++kk) {
            float a[4], b[4];
            *(float4*)a = *(const float4*)&QsT[kk][4 * ty];
            *(float4*)b = *(const float4*)&KV[kk][4 * tx];
#pragma unroll
            for (int i = 0; i < 4; ++i)
#pragma unroll
                for (int j = 0; j < 4; ++j)
                    qk[i][j] = fmaf(a[i], b[j], qk[i][j]);
        }
        // finalize scores + causal mask, write Ps
        {
            const bool diag = (kt == qt);
#pragma unroll
            for (int i = 0; i < 4; ++i) {
                float qni = qn[4 * ty + i];
                float sv[4];
#pragma unroll
                for (int j = 0; j < 4; ++j) {
                    float qkv = qk[i][j];
                    float d2 = qni + kn[4 * tx + j] - 2.f * qkv + EPS_F;
                    float sc = qkv * qkv / d2 * scl;
                    if (diag && (4 * tx + j > 4 * ty + i)) sc = -3.0e38f;
                    sv[j] = sc;
                }
                *(float4*)&Ps[4 * ty + i][4 * tx] =
                    make_float4(sv[0], sv[1], sv[2], sv[3]);
            }
        }
        __syncthreads();
        // online softmax: 4 threads per row
        {
            int r = tid >> 2, part = tid & 3;
            float* prow = &Ps[r][part * 16];
            float4 v[4];
            float mx = -INFINITY;
#pragma unroll
            for (int u = 0; u < 4; ++u) {
                v[u] = *(const float4*)&prow[4 * u];
                mx = fmaxf(mx, fmaxf(fmaxf(v[u].x, v[u].y), fmaxf(v[u].z, v[u].w)));
            }
            mx = fmaxf(mx, __shfl_xor(mx, 1));
            mx = fmaxf(mx, __shfl_xor(mx, 2));
            float mold = mrow[r];
            float mnew = fmaxf(mold, mx);
            float sum = 0.f;
#pragma unroll
            for (int u = 0; u < 4; ++u) {
                v[u].x = __expf(v[u].x - mnew); sum += v[u].x;
                v[u].y = __expf(v[u].y - mnew); sum += v[u].y;
                v[u].z = __expf(v[u].z - mnew); sum += v[u].z;
                v[u].w = __expf(v[u].w - mnew); sum += v[u].w;
                *(float4*)&prow[4 * u] = v[u];
            }
            sum += __shfl_xor(sum, 1);
            sum += __shfl_xor(sum, 2);
            if (part == 0) {
                float sf = __expf(mold - mnew);
                sfrow[r] = sf;
                lrow[r] = lrow[r] * sf + sum;
                mrow[r] = mnew;
            }
        }
        __syncthreads();
        {   // stage V row-major into KV (KsT no longer needed)
            int c = tid >> 2, d0 = (tid & 3) * 16;
            const float* src = &Vh[(kt * 64 + c) * 64 + d0];
#pragma unroll
            for (int u = 0; u < 4; ++u)
                *(float4*)&KV[c][d0 + 4 * u] = *(const float4*)(src + 4 * u);
        }
        __syncthreads();
        // rescale + PV
        {
            float sf[4];
#pragma unroll
            for (int i = 0; i < 4; ++i) sf[i] = sfrow[4 * ty + i];
#pragma unroll
            for (int i = 0; i < 4; ++i)
#pragma unroll
                for (int j = 0; j < 4; ++j) accO[i][j] *= sf[i];
#pragma unroll
            for (int c4 = 0; c4 < 16; ++c4) {
                float p4[4][4];
#pragma unroll
                for (int i = 0; i < 4; ++i)
                    *(float4*)p4[i] = *(const float4*)&Ps[4 * ty + i][4 * c4];
#pragma unroll
                for (int cc = 0; cc < 4; ++cc) {
                    float4 vv = *(const float4*)&KV[4 * c4 + cc][4 * tx];
                    float vr[4] = {vv.x, vv.y, vv.z, vv.w};
#pragma unroll
                    for (int i = 0; i < 4; ++i)
#pragma unroll
                        for (int j = 0; j < 4; ++j)
                            accO[i][j] = fmaf(p4[i][cc], vr[j], accO[i][j]);
                }
            }
        }
    }
    // write attention output (B,H,S,HD)
#pragma unroll
    for (int i = 0; i < 4; ++i) {
        float linv = 1.f / lrow[4 * ty + i];
        int srow = qt * 64 + 4 * ty + i;
        float4 o = make_float4(accO[i][0] * linv, accO[i][1] * linv,
                               accO[i][2] * linv, accO[i][3] * linv);
        *(float4*)&AO[((size_t)bh * SS + srow) * 64 + 4 * tx] = o;
    }
}

// ---------------------------------------------------------------------------
// Output projection: out = AO(regathered to (b,s,h*hd)) @ Wo. Same GEMM shape.
// ---------------------------------------------------------------------------
__global__ __launch_bounds__(256) void k_proj(const float* __restrict__ AO,
        const float* __restrict__ Wo, float* __restrict__ out) {
    const int m0 = blockIdx.x * 128;
    const int n0 = blockIdx.y * 128;
    __shared__ float AsT[16][128];
    __shared__ float Bs[16][128];
    const int tid = threadIdx.x;
    const int ty = tid >> 4, tx = tid & 15;
    const int ar = tid >> 1, akc = (tid & 1) * 8;
    const int bk = tid >> 4, bc = (tid & 15) * 8;
    const int mg = m0 + ar;
    const int bidx = mg >> 11, srow = mg & (SS - 1);
    float acc[2][2][4][4] = {};
    for (int k0 = 0; k0 < DD; k0 += 16) {
        int k = k0 + akc;
        int h = k >> 6, hd = k & 63;   // 8-aligned, never crosses a head
        const float* ap = &AO[(((size_t)bidx * HH + h) * SS + srow) * 64 + hd];
        float4 a0 = *(const float4*)ap;
        float4 a1 = *(const float4*)(ap + 4);
        float4 b0 = *(const float4*)&Wo[(k0 + bk) * DD + n0 + bc];
        float4 b1 = *(const float4*)&Wo[(k0 + bk) * DD + n0 + bc + 4];
        __syncthreads();
        AsT[akc + 0][ar] = a0.x; AsT[akc + 1][ar] = a0.y;
        AsT[akc + 2][ar] = a0.z; AsT[akc + 3][ar] = a0.w;
        AsT[akc + 4][ar] = a1.x; AsT[akc + 5][ar] = a1.y;
        AsT[akc + 6][ar] = a1.z; AsT[akc + 7][ar] = a1.w;
        *(float4*)&Bs[bk][bc] = b0;
        *(float4*)&Bs[bk][bc + 4] = b1;
        __syncthreads();
#pragma unroll
        for (int kk = 0; kk < 16; ++kk) {
            float aa[2][4], bb2[2][4];
            *(float4*)aa[0] = *(const float4*)&AsT[kk][4 * ty];
            *(float4*)aa[1] = *(const float4*)&AsT[kk][64 + 4 * ty];
            *(float4*)bb2[0] = *(const float4*)&Bs[kk][4 * tx];
            *(float4*)bb2[1] = *(const float4*)&Bs[kk][64 + 4 * tx];
#pragma unroll
            for (int qi = 0; qi < 2; ++qi)
#pragma unroll
                for (int qj = 0; qj < 2; ++qj)
#pragma unroll
                    for (int i = 0; i < 4; ++i)
#pragma unroll
                        for (int j = 0; j < 4; ++j)
                            acc[qi][qj][i][j] =
                                fmaf(aa[qi][i], bb2[qj][j], acc[qi][qj][i][j]);
        }
    }
#pragma unroll
    for (int qi = 0; qi < 2; ++qi)
#pragma unroll
        for (int i = 0; i < 4; ++i) {
            int mgg = m0 + qi * 64 + 4 * ty + i;
#pragma unroll
            for (int qj = 0; qj < 2; ++qj) {
                int ng = n0 + qj * 64 + 4 * tx;
                float4 st = make_float4(acc[qi][qj][i][0], acc[qi][qj][i][1],
                                        acc[qi][qj][i][2], acc[qi][qj][i][3]);
                *(float4*)&out[(size_t)mgg * DD + ng] = st;
            }
        }
}

extern "C" void kernel_launch(void* const* d_in, const int* in_sizes, int n_in,
                              void* d_out, int out_size, void* d_ws, size_t ws_size,
                              hipStream_t stream) {
    const float* x     = (const float*)d_in[0];
    const float* Wq    = (const float*)d_in[1];
    const float* Wk    = (const float*)d_in[2];
    const float* Wv    = (const float*)d_in[3];
    const float* Wo    = (const float*)d_in[4];
    const float* alpha = (const float*)d_in[5];
    float* out = (float*)d_out;

    float* ws   = (float*)d_ws;
    float* cosT = ws;                            // S*32
    float* sinT = ws + SS * 32;                  // S*32
    float* Qg   = ws + SS * 64;                  // M*D each, (B,H,S,HD)
    float* Kg   = Qg + (size_t)MM * DD;
    float* Vg   = Kg + (size_t)MM * DD;
    float* AO   = Vg + (size_t)MM * DD;

    hipLaunchKernelGGL(k_rope_table, dim3(SS * 32 / 256), dim3(256), 0, stream,
                       cosT, sinT);
    hipLaunchKernelGGL(k_qkv, dim3(MM / 128, DD / 128, 3), dim3(256), 0, stream,
                       x, Wq, Wk, Wv, cosT, sinT, Qg, Kg, Vg);
    hipLaunchKernelGGL(k_attn, dim3(SS / 64, BB * HH), dim3(256), 0, stream,
                       Qg, Kg, Vg, alpha, AO);
    hipLaunchKernelGGL(k_proj, dim3(MM / 128, DD / 128), dim3(256), 0, stream,
                       AO, Wo, out);
}

// Round 2
// 474.626 us; speedup vs baseline: 2.2760x; 2.2760x over previous
//
#include <hip/hip_runtime.h>
#include <cmath>

#define BB 2
#define SS 2048
#define DD 1024
#define HH 16
#define HDD 64
#define MM (BB * SS)
#define BH (BB * HH)

typedef _Float16 f16;
typedef _Float16 f16x2 __attribute__((ext_vector_type(2)));
typedef _Float16 f16x4 __attribute__((ext_vector_type(4)));
typedef _Float16 f16x8 __attribute__((ext_vector_type(8)));
typedef float f32x4 __attribute__((ext_vector_type(4)));

#define MFMA(A, B, C) __builtin_amdgcn_mfma_f32_16x16x32_f16(A, B, C, 0, 0, 0)

__device__ __forceinline__ void gload16(const void* g, void* l) {
    __builtin_amdgcn_global_load_lds(
        (const __attribute__((address_space(1))) void*)g,
        (__attribute__((address_space(3))) void*)l, 16, 0, 0);
}

// ---------------------------------------------------------------------------
// RoPE cos/sin table (fp64 trig to match numpy).
// ---------------------------------------------------------------------------
__global__ __launch_bounds__(256) void k_rope_table(float* __restrict__ cosT,
                                                    float* __restrict__ sinT) {
    int idx = blockIdx.x * 256 + threadIdx.x;
    int s = idx >> 5, j = idx & 31;
    double inv = pow(10000.0, -(double)(2 * j) / 64.0);
    double ang = (double)s * inv;
    cosT[idx] = (float)cos(ang);
    sinT[idx] = (float)sin(ang);
}

// ---------------------------------------------------------------------------
// x (fp32, M x D) -> xb (fp16, same layout)
// ---------------------------------------------------------------------------
__global__ __launch_bounds__(256) void k_cast_x(const float* __restrict__ x,
                                                f16* __restrict__ xb) {
    int i = (blockIdx.x * 256 + threadIdx.x) * 8;
    float4 a = *(const float4*)&x[i];
    float4 b = *(const float4*)&x[i + 4];
    f16x8 o = {(f16)a.x, (f16)a.y, (f16)a.z, (f16)a.w,
               (f16)b.x, (f16)b.y, (f16)b.z, (f16)b.w};
    *(f16x8*)&xb[i] = o;
}

// ---------------------------------------------------------------------------
// W (fp32, K x N) -> Wt (fp16, N x K)  for Wq,Wk,Wv,Wo (z = 0..3)
// ---------------------------------------------------------------------------
__global__ __launch_bounds__(256) void k_wcast(const float* __restrict__ Wq,
        const float* __restrict__ Wk, const float* __restrict__ Wv,
        const float* __restrict__ Wo, f16* __restrict__ WtAll) {
    const int z = blockIdx.z;
    const float* __restrict__ src = (z == 0) ? Wq : (z == 1) ? Wk
                                   : (z == 2) ? Wv : Wo;
    f16* __restrict__ dst = WtAll + (size_t)z * DD * DD;
    const int kk0 = blockIdx.x * 64, nn0 = blockIdx.y * 64;
    __shared__ float t[64][65];
    const int tid = threadIdx.x;
    const int rr = tid >> 4, c4 = (tid & 15) * 4;
#pragma unroll
    for (int p = 0; p < 4; ++p) {
        float4 v = *(const float4*)&src[(size_t)(kk0 + p * 16 + rr) * DD + nn0 + c4];
        t[p * 16 + rr][c4 + 0] = v.x; t[p * 16 + rr][c4 + 1] = v.y;
        t[p * 16 + rr][c4 + 2] = v.z; t[p * 16 + rr][c4 + 3] = v.w;
    }
    __syncthreads();
#pragma unroll
    for (int p = 0; p < 4; ++p) {
        int n = p * 16 + rr;
        f16x4 o = {(f16)t[c4 + 0][n], (f16)t[c4 + 1][n],
                   (f16)t[c4 + 2][n], (f16)t[c4 + 3][n]};
        *(f16x4*)&dst[(size_t)(nn0 + n) * DD + kk0 + c4] = o;
    }
}

// ---------------------------------------------------------------------------
// QKV GEMM (fp16 MFMA, 128x128 tile, BK=32, global_load_lds staging).
// Epilogue: RoPE (Q,K) via shfl_xor pairing + fp32 row norms, store (B,H,S,HD).
// ---------------------------------------------------------------------------
__global__ __launch_bounds__(256) void k_qkv(const f16* __restrict__ xb,
        const f16* __restrict__ WtAll,
        const float* __restrict__ cosT, const float* __restrict__ sinT,
        f16* __restrict__ Qh, f16* __restrict__ Kh, f16* __restrict__ Vh,
        float* __restrict__ qn, float* __restrict__ kn) {
    const int z = blockIdx.z;
    const f16* __restrict__ Wt = WtAll + (size_t)z * DD * DD;
    f16* __restrict__ dst = (z == 0) ? Qh : (z == 1) ? Kh : Vh;
    const int m0 = blockIdx.x * 128;
    const int n0 = blockIdx.y * 128;
    __shared__ f16 As[128 * 32];
    __shared__ f16 Bs[128 * 32];
    const int tid = threadIdx.x;
    const int wv = tid >> 6, ln = tid & 63;
    const int wm = wv >> 1, wn = wv & 1;
    const int lg = ln >> 4, lr = ln & 15;
    f32x4 acc[4][4] = {};
    for (int k0 = 0; k0 < DD; k0 += 32) {
        __syncthreads();
#pragma unroll
        for (int u = 0; u < 2; ++u) {
            int e = u * 2048 + wv * 512 + ln * 8;
            int r = e >> 5, c = e & 31;
            gload16(&xb[(size_t)(m0 + r) * DD + k0 + c], &As[e]);
            gload16(&Wt[(size_t)(n0 + r) * DD + k0 + c], &Bs[e]);
        }
        __syncthreads();
        f16x8 af[4], bf[4];
#pragma unroll
        for (int mt = 0; mt < 4; ++mt)
            af[mt] = *(const f16x8*)&As[(wm * 64 + mt * 16 + lr) * 32 + lg * 8];
#pragma unroll
        for (int nt = 0; nt < 4; ++nt)
            bf[nt] = *(const f16x8*)&Bs[(wn * 64 + nt * 16 + lr) * 32 + lg * 8];
#pragma unroll
        for (int mt = 0; mt < 4; ++mt)
#pragma unroll
            for (int nt = 0; nt < 4; ++nt)
                acc[mt][nt] = MFMA(af[mt], bf[nt], acc[mt][nt]);
    }
    const bool isv = (z == 2);
#pragma unroll
    for (int mt = 0; mt < 4; ++mt) {
        float nsum[4] = {0.f, 0.f, 0.f, 0.f};
#pragma unroll
        for (int reg = 0; reg < 4; ++reg) {
            int gr = m0 + wm * 64 + mt * 16 + lg * 4 + reg;
            int b = gr >> 11, s = gr & (SS - 1);
#pragma unroll
            for (int nt = 0; nt < 4; ++nt) {
                int gc = n0 + wn * 64 + nt * 16 + lr;
                int h = gc >> 6, d = gc & 63;
                float v = acc[mt][nt][reg];
                if (!isv) {
                    float p = __shfl_xor(v, 1);
                    int pr = d >> 1;
                    float cz = cosT[s * 32 + pr], sz = sinT[s * 32 + pr];
                    if ((lr & 1) == 0) {
                        float oe = v * cz - p * sz;
                        float oo = v * sz + p * cz;
                        f16x2 st; st[0] = (f16)oe; st[1] = (f16)oo;
                        *(f16x2*)&dst[(((size_t)b * HH + h) * SS + s) * HDD + d] = st;
                        nsum[reg] += oe * oe + oo * oo;
                    }
                } else {
                    dst[(((size_t)b * HH + h) * SS + s) * HDD + d] = (f16)v;
                }
            }
        }
        if (!isv) {
#pragma unroll
            for (int reg = 0; reg < 4; ++reg) {
                float ns = nsum[reg];
                ns += __shfl_xor(ns, 1); ns += __shfl_xor(ns, 2);
                ns += __shfl_xor(ns, 4); ns += __shfl_xor(ns, 8);
                if (lr == 0) {
                    int gr = m0 + wm * 64 + mt * 16 + lg * 4 + reg;
                    int b = gr >> 11, s = gr & (SS - 1);
                    int h = (n0 + wn * 64) >> 6;
                    float* np = (z == 0) ? qn : kn;
                    np[((size_t)b * HH + h) * SS + s] = ns;
                }
            }
        }
    }
}

// ---------------------------------------------------------------------------
// Vh (B,H,S,HD) -> Vt (B,H,HD,S)
// ---------------------------------------------------------------------------
__global__ __launch_bounds__(256) void k_vt(const f16* __restrict__ Vh,
                                            f16* __restrict__ Vt) {
    const int s0 = blockIdx.x * 64;
    const int bh = blockIdx.y;
    __shared__ f16 t[64][80];
    const int tid = threadIdx.x;
    const int sr = tid >> 3, d0 = (tid & 7) * 8;
#pragma unroll
    for (int p = 0; p < 2; ++p) {
        f16x8 v = *(const f16x8*)&Vh[((size_t)bh * SS + s0 + p * 32 + sr) * HDD + d0];
#pragma unroll
        for (int j = 0; j < 8; ++j) t[d0 + j][p * 32 + sr] = v[j];
    }
    __syncthreads();
    const int dr = tid >> 3, s4 = (tid & 7) * 8;
#pragma unroll
    for (int p = 0; p < 2; ++p) {
        f16x8 o = *(const f16x8*)&t[p * 32 + dr][s4];
        *(f16x8*)&Vt[((size_t)bh * HDD + p * 32 + dr) * SS + s0 + s4] = o;
    }
}

// ---------------------------------------------------------------------------
// Yat attention: 4 independent waves/block, 16 Q-rows per wave, KV tile 64.
// MFMA QK^T -> in-register online softmax -> P via swizzled LDS -> MFMA PV.
// No __syncthreads in the k-loop (waves share nothing).
// ---------------------------------------------------------------------------
__global__ __launch_bounds__(256) void k_attn(const f16* __restrict__ Qh,
        const f16* __restrict__ Kh, const f16* __restrict__ Vt,
        const float* __restrict__ qn, const float* __restrict__ kn,
        const float* __restrict__ alpha, f16* __restrict__ AO) {
    const int qt = (SS / 64 - 1) - blockIdx.x;   // longest first
    const int bh = blockIdx.y;
    const int tid = threadIdx.x;
    const int wv = tid >> 6, ln = tid & 63;
    const int lg = ln >> 4, lr = ln & 15;
    const int r0 = qt * 64 + wv * 16;
    __shared__ f16 Pl[4096];                     // 4 waves x 16x64 fp16
    const float scl = powf(8.0f / logf(65.0f), alpha[0]);
    const f16* __restrict__ Qp = Qh + (size_t)bh * SS * HDD;
    const f16* __restrict__ Kp = Kh + (size_t)bh * SS * HDD;
    const f16* __restrict__ Vp = Vt + (size_t)bh * HDD * SS;

    f16x8 aq0 = *(const f16x8*)&Qp[(size_t)(r0 + lr) * HDD + lg * 8];
    f16x8 aq1 = *(const f16x8*)&Qp[(size_t)(r0 + lr) * HDD + 32 + lg * 8];
    float qnr[4];
#pragma unroll
    for (int reg = 0; reg < 4; ++reg)
        qnr[reg] = qn[(size_t)bh * SS + r0 + lg * 4 + reg];
    float m_[4], l_[4];
    f32x4 accO[4] = {};
#pragma unroll
    for (int reg = 0; reg < 4; ++reg) { m_[reg] = -INFINITY; l_[reg] = 0.f; }

    for (int kt = 0; kt <= qt; ++kt) {
        const int kb = kt * 64;
        f32x4 c[4];
#pragma unroll
        for (int nt = 0; nt < 4; ++nt) {
            f16x8 bk0 = *(const f16x8*)&Kp[(size_t)(kb + nt * 16 + lr) * HDD + lg * 8];
            f16x8 bk1 = *(const f16x8*)&Kp[(size_t)(kb + nt * 16 + lr) * HDD + 32 + lg * 8];
            f32x4 t = {};
            t = MFMA(aq0, bk0, t);
            t = MFMA(aq1, bk1, t);
            c[nt] = t;
        }
        float knv[4];
#pragma unroll
        for (int nt = 0; nt < 4; ++nt)
            knv[nt] = kn[(size_t)bh * SS + kb + nt * 16 + lr];
        const bool diag = (kt == qt);
        float sc[4][4];
#pragma unroll
        for (int nt = 0; nt < 4; ++nt)
#pragma unroll
            for (int reg = 0; reg < 4; ++reg) {
                float qk = c[nt][reg];
                float d2 = qnr[reg] + knv[nt] - 2.0f * qk + 1e-5f;
                float v = qk * qk / d2 * scl;
                if (diag && (nt * 16 + lr > wv * 16 + lg * 4 + reg)) v = -3.0e38f;
                sc[nt][reg] = v;
            }
        float corr[4];
#pragma unroll
        for (int reg = 0; reg < 4; ++reg) {
            float mx = fmaxf(fmaxf(sc[0][reg], sc[1][reg]),
                             fmaxf(sc[2][reg], sc[3][reg]));
            mx = fmaxf(mx, __shfl_xor(mx, 1));
            mx = fmaxf(mx, __shfl_xor(mx, 2));
            mx = fmaxf(mx, __shfl_xor(mx, 4));
            mx = fmaxf(mx, __shfl_xor(mx, 8));
            float mnew = fmaxf(m_[reg], mx);
            float co = __expf(m_[reg] - mnew);
            float ps = 0.f;
#pragma unroll
            for (int nt = 0; nt < 4; ++nt) {
                float p = __expf(sc[nt][reg] - mnew);
                sc[nt][reg] = p;
                ps += p;
            }
            ps += __shfl_xor(ps, 1); ps += __shfl_xor(ps, 2);
            ps += __shfl_xor(ps, 4); ps += __shfl_xor(ps, 8);
            l_[reg] = l_[reg] * co + ps;
            m_[reg] = mnew;
            corr[reg] = co;
        }
#pragma unroll
        for (int dt = 0; dt < 4; ++dt)
#pragma unroll
            for (int reg = 0; reg < 4; ++reg) accO[dt][reg] *= corr[reg];
        // P -> LDS (fp16, XOR-swizzled rows)
#pragma unroll
        for (int nt = 0; nt < 4; ++nt)
#pragma unroll
            for (int reg = 0; reg < 4; ++reg) {
                int prr = lg * 4 + reg;
                int byt = wv * 2048 + ((prr * 128 + (nt * 16 + lr) * 2) ^ ((prr & 7) << 4));
                Pl[byt >> 1] = (f16)sc[nt][reg];
            }
        f16x8 pa0, pa1;
        {
            int b0 = wv * 2048 + ((lr * 128 + lg * 16) ^ ((lr & 7) << 4));
            int b1 = wv * 2048 + ((lr * 128 + 64 + lg * 16) ^ ((lr & 7) << 4));
            pa0 = *(const f16x8*)&Pl[b0 >> 1];
            pa1 = *(const f16x8*)&Pl[b1 >> 1];
        }
#pragma unroll
        for (int dt = 0; dt < 4; ++dt) {
            f16x8 bv0 = *(const f16x8*)&Vp[(size_t)(dt * 16 + lr) * SS + kb + lg * 8];
            f16x8 bv1 = *(const f16x8*)&Vp[(size_t)(dt * 16 + lr) * SS + kb + 32 + lg * 8];
            accO[dt] = MFMA(pa0, bv0, accO[dt]);
            accO[dt] = MFMA(pa1, bv1, accO[dt]);
        }
    }
#pragma unroll
    for (int reg = 0; reg < 4; ++reg) {
        float li = 1.0f / l_[reg];
        int row = r0 + lg * 4 + reg;
#pragma unroll
        for (int dt = 0; dt < 4; ++dt)
            AO[((size_t)bh * SS + row) * HDD + dt * 16 + lr] =
                (f16)(accO[dt][reg] * li);
    }
}

// ---------------------------------------------------------------------------
// out = AO(gathered to (b,s,h*hd)) @ Wo  (fp16 MFMA, fp32 out)
// ---------------------------------------------------------------------------
__global__ __launch_bounds__(256) void k_proj(const f16* __restrict__ AO,
        const f16* __restrict__ Wot, float* __restrict__ out) {
    const int m0 = blockIdx.x * 128;
    const int n0 = blockIdx.y * 128;
    __shared__ f16 As[128 * 32];
    __shared__ f16 Bs[128 * 32];
    const int tid = threadIdx.x;
    const int wv = tid >> 6, ln = tid & 63;
    const int wm = wv >> 1, wn = wv & 1;
    const int lg = ln >> 4, lr = ln & 15;
    f32x4 acc[4][4] = {};
    for (int k0 = 0; k0 < DD; k0 += 32) {
        __syncthreads();
#pragma unroll
        for (int u = 0; u < 2; ++u) {
            int e = u * 2048 + wv * 512 + ln * 8;
            int r = e >> 5, c = e & 31;
            int gm = m0 + r, b = gm >> 11, s = gm & (SS - 1);
            int k = k0 + c, h = k >> 6, d = k & 63;
            gload16(&AO[(((size_t)b * HH + h) * SS + s) * HDD + d], &As[e]);
            gload16(&Wot[(size_t)(n0 + r) * DD + k0 + c], &Bs[e]);
        }
        __syncthreads();
        f16x8 af[4], bf[4];
#pragma unroll
        for (int mt = 0; mt < 4; ++mt)
            af[mt] = *(const f16x8*)&As[(wm * 64 + mt * 16 + lr) * 32 + lg * 8];
#pragma unroll
        for (int nt = 0; nt < 4; ++nt)
            bf[nt] = *(const f16x8*)&Bs[(wn * 64 + nt * 16 + lr) * 32 + lg * 8];
#pragma unroll
        for (int mt = 0; mt < 4; ++mt)
#pragma unroll
            for (int nt = 0; nt < 4; ++nt)
                acc[mt][nt] = MFMA(af[mt], bf[nt], acc[mt][nt]);
    }
#pragma unroll
    for (int mt = 0; mt < 4; ++mt)
#pragma unroll
        for (int reg = 0; reg < 4; ++reg) {
            int gr = m0 + wm * 64 + mt * 16 + lg * 4 + reg;
#pragma unroll
            for (int nt = 0; nt < 4; ++nt) {
                int gc = n0 + wn * 64 + nt * 16 + lr;
                out[(size_t)gr * DD + gc] = acc[mt][nt][reg];
            }
        }
}

extern "C" void kernel_launch(void* const* d_in, const int* in_sizes, int n_in,
                              void* d_out, int out_size, void* d_ws, size_t ws_size,
                              hipStream_t stream) {
    const float* x     = (const float*)d_in[0];
    const float* Wq    = (const float*)d_in[1];
    const float* Wk    = (const float*)d_in[2];
    const float* Wv    = (const float*)d_in[3];
    const float* Wo    = (const float*)d_in[4];
    const float* alpha = (const float*)d_in[5];
    float* out = (float*)d_out;

    float* cosT = (float*)d_ws;
    float* sinT = cosT + SS * 32;
    float* qn   = sinT + SS * 32;
    float* kn   = qn + (size_t)BH * SS;
    f16* xb     = (f16*)(kn + (size_t)BH * SS);
    f16* WtAll  = xb + (size_t)MM * DD;
    f16* Qh     = WtAll + (size_t)4 * DD * DD;
    f16* Kh     = Qh + (size_t)MM * DD;
    f16* Vh     = Kh + (size_t)MM * DD;
    f16* Vt     = Vh + (size_t)MM * DD;
    f16* AO     = Vt + (size_t)MM * DD;
    f16* Wot    = WtAll + (size_t)3 * DD * DD;

    hipLaunchKernelGGL(k_rope_table, dim3(SS * 32 / 256), dim3(256), 0, stream,
                       cosT, sinT);
    hipLaunchKernelGGL(k_cast_x, dim3(MM * DD / (256 * 8)), dim3(256), 0, stream,
                       x, xb);
    hipLaunchKernelGGL(k_wcast, dim3(16, 16, 4), dim3(256), 0, stream,
                       Wq, Wk, Wv, Wo, WtAll);
    hipLaunchKernelGGL(k_qkv, dim3(MM / 128, DD / 128, 3), dim3(256), 0, stream,
                       xb, WtAll, cosT, sinT, Qh, Kh, Vh, qn, kn);
    hipLaunchKernelGGL(k_vt, dim3(SS / 64, BH), dim3(256), 0, stream, Vh, Vt);
    hipLaunchKernelGGL(k_attn, dim3(SS / 64, BH), dim3(256), 0, stream,
                       Qh, Kh, Vt, qn, kn, alpha, AO);
    hipLaunchKernelGGL(k_proj, dim3(MM / 128, DD / 128), dim3(256), 0, stream,
                       AO, Wot, out);
}

// Round 4
// 290.636 us; speedup vs baseline: 3.7168x; 1.6331x over previous
//
#include <hip/hip_runtime.h>
#include <cmath>

#define BB 2
#define SS 2048
#define DD 1024
#define HH 16
#define HDD 64
#define MM (BB * SS)
#define BH (BB * HH)

typedef _Float16 f16;
typedef _Float16 f16x2 __attribute__((ext_vector_type(2)));
typedef _Float16 f16x4 __attribute__((ext_vector_type(4)));
typedef _Float16 f16x8 __attribute__((ext_vector_type(8)));
typedef float f32x4 __attribute__((ext_vector_type(4)));
typedef float f32x16 __attribute__((ext_vector_type(16)));
typedef unsigned int u32x4 __attribute__((ext_vector_type(4)));

#define MFMA(A, B, C) __builtin_amdgcn_mfma_f32_16x16x32_f16(A, B, C, 0, 0, 0)
#define MFMA32(A, B, C) __builtin_amdgcn_mfma_f32_32x32x16_f16(A, B, C, 0, 0, 0)

__device__ __forceinline__ void gload16(const void* g, void* l) {
    __builtin_amdgcn_global_load_lds(
        (const __attribute__((address_space(1))) void*)g,
        (__attribute__((address_space(3))) void*)l, 16, 0, 0);
}

__device__ __forceinline__ unsigned pk(float a, float b) {
    auto h = __builtin_amdgcn_cvt_pkrtz(a, b);   // __fp16 ext_vector(2)
    return __builtin_bit_cast(unsigned, h);
}

// Build the PV A-fragment (16 consecutive k) from 8 per-lane P values whose
// k-pattern is (r&3)+8*(r>>2)+4*hi. Half-exchange via shfl_xor(32)+select.
__device__ __forceinline__ f16x8 pack8(float p0, float p1, float p2, float p3,
                                       float p4, float p5, float p6, float p7,
                                       int hi) {
    unsigned wa = pk(p0, p1), wa2 = pk(p2, p3);
    unsigned wb = pk(p4, p5), wb2 = pk(p6, p7);
    unsigned xa = __shfl_xor(wa, 32), xa2 = __shfl_xor(wa2, 32);
    unsigned xb = __shfl_xor(wb, 32), xb2 = __shfl_xor(wb2, 32);
    unsigned w0 = hi ? xb : wa;
    unsigned w1 = hi ? xb2 : wa2;
    unsigned w2 = hi ? wb : xa;
    unsigned w3 = hi ? wb2 : xa2;
    u32x4 w = {w0, w1, w2, w3};
    return __builtin_bit_cast(f16x8, w);
}

// ---------------------------------------------------------------------------
// RoPE cos/sin table (fp64 trig to match numpy).
// ---------------------------------------------------------------------------
__global__ __launch_bounds__(256) void k_rope_table(float* __restrict__ cosT,
                                                    float* __restrict__ sinT) {
    int idx = blockIdx.x * 256 + threadIdx.x;
    int s = idx >> 5, j = idx & 31;
    double inv = pow(10000.0, -(double)(2 * j) / 64.0);
    double ang = (double)s * inv;
    cosT[idx] = (float)cos(ang);
    sinT[idx] = (float)sin(ang);
}

// ---------------------------------------------------------------------------
// x (fp32, M x D) -> xb (fp16, same layout)
// ---------------------------------------------------------------------------
__global__ __launch_bounds__(256) void k_cast_x(const float* __restrict__ x,
                                                f16* __restrict__ xb) {
    int i = (blockIdx.x * 256 + threadIdx.x) * 8;
    float4 a = *(const float4*)&x[i];
    float4 b = *(const float4*)&x[i + 4];
    f16x8 o = {(f16)a.x, (f16)a.y, (f16)a.z, (f16)a.w,
               (f16)b.x, (f16)b.y, (f16)b.z, (f16)b.w};
    *(f16x8*)&xb[i] = o;
}

// ---------------------------------------------------------------------------
// W (fp32, K x N) -> Wt (fp16, N x K)  for Wq,Wk,Wv,Wo (z = 0..3)
// ---------------------------------------------------------------------------
__global__ __launch_bounds__(256) void k_wcast(const float* __restrict__ Wq,
        const float* __restrict__ Wk, const float* __restrict__ Wv,
        const float* __restrict__ Wo, f16* __restrict__ WtAll) {
    const int z = blockIdx.z;
    const float* __restrict__ src = (z == 0) ? Wq : (z == 1) ? Wk
                                   : (z == 2) ? Wv : Wo;
    f16* __restrict__ dst = WtAll + (size_t)z * DD * DD;
    const int kk0 = blockIdx.x * 64, nn0 = blockIdx.y * 64;
    __shared__ float t[64][65];
    const int tid = threadIdx.x;
    const int rr = tid >> 4, c4 = (tid & 15) * 4;
#pragma unroll
    for (int p = 0; p < 4; ++p) {
        float4 v = *(const float4*)&src[(size_t)(kk0 + p * 16 + rr) * DD + nn0 + c4];
        t[p * 16 + rr][c4 + 0] = v.x; t[p * 16 + rr][c4 + 1] = v.y;
        t[p * 16 + rr][c4 + 2] = v.z; t[p * 16 + rr][c4 + 3] = v.w;
    }
    __syncthreads();
#pragma unroll
    for (int p = 0; p < 4; ++p) {
        int n = p * 16 + rr;
        f16x4 o = {(f16)t[c4 + 0][n], (f16)t[c4 + 1][n],
                   (f16)t[c4 + 2][n], (f16)t[c4 + 3][n]};
        *(f16x4*)&dst[(size_t)(nn0 + n) * DD + kk0 + c4] = o;
    }
}

// ---------------------------------------------------------------------------
// QKV GEMM (fp16 MFMA, 128x128 tile, BK=32, global_load_lds staging).
// Epilogue: RoPE (Q,K) via shfl_xor pairing + fp32 row norms, store (B,H,S,HD).
// ---------------------------------------------------------------------------
__global__ __launch_bounds__(256) void k_qkv(const f16* __restrict__ xb,
        const f16* __restrict__ WtAll,
        const float* __restrict__ cosT, const float* __restrict__ sinT,
        f16* __restrict__ Qh, f16* __restrict__ Kh, f16* __restrict__ Vh,
        float* __restrict__ qn, float* __restrict__ kn) {
    const int z = blockIdx.z;
    const f16* __restrict__ Wt = WtAll + (size_t)z * DD * DD;
    f16* __restrict__ dst = (z == 0) ? Qh : (z == 1) ? Kh : Vh;
    const int m0 = blockIdx.x * 128;
    const int n0 = blockIdx.y * 128;
    __shared__ f16 As[128 * 32];
    __shared__ f16 Bs[128 * 32];
    const int tid = threadIdx.x;
    const int wv = tid >> 6, ln = tid & 63;
    const int wm = wv >> 1, wn = wv & 1;
    const int lg = ln >> 4, lr = ln & 15;
    f32x4 acc[4][4] = {};
    for (int k0 = 0; k0 < DD; k0 += 32) {
        __syncthreads();
#pragma unroll
        for (int u = 0; u < 2; ++u) {
            int e = u * 2048 + wv * 512 + ln * 8;
            int r = e >> 5, c = e & 31;
            gload16(&xb[(size_t)(m0 + r) * DD + k0 + c], &As[e]);
            gload16(&Wt[(size_t)(n0 + r) * DD + k0 + c], &Bs[e]);
        }
        __syncthreads();
        f16x8 af[4], bf[4];
#pragma unroll
        for (int mt = 0; mt < 4; ++mt)
            af[mt] = *(const f16x8*)&As[(wm * 64 + mt * 16 + lr) * 32 + lg * 8];
#pragma unroll
        for (int nt = 0; nt < 4; ++nt)
            bf[nt] = *(const f16x8*)&Bs[(wn * 64 + nt * 16 + lr) * 32 + lg * 8];
#pragma unroll
        for (int mt = 0; mt < 4; ++mt)
#pragma unroll
            for (int nt = 0; nt < 4; ++nt)
                acc[mt][nt] = MFMA(af[mt], bf[nt], acc[mt][nt]);
    }
    const bool isv = (z == 2);
#pragma unroll
    for (int mt = 0; mt < 4; ++mt) {
        float nsum[4] = {0.f, 0.f, 0.f, 0.f};
#pragma unroll
        for (int reg = 0; reg < 4; ++reg) {
            int gr = m0 + wm * 64 + mt * 16 + lg * 4 + reg;
            int b = gr >> 11, s = gr & (SS - 1);
#pragma unroll
            for (int nt = 0; nt < 4; ++nt) {
                int gc = n0 + wn * 64 + nt * 16 + lr;
                int h = gc >> 6, d = gc & 63;
                float v = acc[mt][nt][reg];
                if (!isv) {
                    float p = __shfl_xor(v, 1);
                    int pr = d >> 1;
                    float cz = cosT[s * 32 + pr], sz = sinT[s * 32 + pr];
                    if ((lr & 1) == 0) {
                        float oe = v * cz - p * sz;
                        float oo = v * sz + p * cz;
                        f16x2 st; st[0] = (f16)oe; st[1] = (f16)oo;
                        *(f16x2*)&dst[(((size_t)b * HH + h) * SS + s) * HDD + d] = st;
                        nsum[reg] += oe * oe + oo * oo;
                    }
                } else {
                    dst[(((size_t)b * HH + h) * SS + s) * HDD + d] = (f16)v;
                }
            }
        }
        if (!isv) {
#pragma unroll
            for (int reg = 0; reg < 4; ++reg) {
                float ns = nsum[reg];
                ns += __shfl_xor(ns, 1); ns += __shfl_xor(ns, 2);
                ns += __shfl_xor(ns, 4); ns += __shfl_xor(ns, 8);
                if (lr == 0) {
                    int gr = m0 + wm * 64 + mt * 16 + lg * 4 + reg;
                    int b = gr >> 11, s = gr & (SS - 1);
                    int h = (n0 + wn * 64) >> 6;
                    float* np = (z == 0) ? qn : kn;
                    np[((size_t)b * HH + h) * SS + s] = ns;
                }
            }
        }
    }
}

// ---------------------------------------------------------------------------
// Vh (B,H,S,HD) -> Vt (B,H,HD,S)
// ---------------------------------------------------------------------------
__global__ __launch_bounds__(256) void k_vt(const f16* __restrict__ Vh,
                                            f16* __restrict__ Vt) {
    const int s0 = blockIdx.x * 64;
    const int bh = blockIdx.y;
    __shared__ f16 t[64][80];
    const int tid = threadIdx.x;
    const int sr = tid >> 3, d0 = (tid & 7) * 8;
#pragma unroll
    for (int p = 0; p < 2; ++p) {
        f16x8 v = *(const f16x8*)&Vh[((size_t)bh * SS + s0 + p * 32 + sr) * HDD + d0];
#pragma unroll
        for (int j = 0; j < 8; ++j) t[d0 + j][p * 32 + sr] = v[j];
    }
    __syncthreads();
    const int dr = tid >> 3, s4 = (tid & 7) * 8;
#pragma unroll
    for (int p = 0; p < 2; ++p) {
        f16x8 o = *(const f16x8*)&t[p * 32 + dr][s4];
        *(f16x8*)&Vt[((size_t)bh * HDD + p * 32 + dr) * SS + s0 + s4] = o;
    }
}

// ---------------------------------------------------------------------------
// Yat attention, swapped-QK^T 32x32x16 structure.
// One wave = 32 q-rows of one (b,h); lane owns q=lane&31 (hi = lane>>5 pair).
// S^T = mfma(K,Q): lane-local row softmax (in-register + 1 shfl_xor(32)).
// P repacked in-register (cvt_pkrtz + half-exchange) -> PV mfma. Zero LDS.
// ---------------------------------------------------------------------------
__global__ __launch_bounds__(256, 2) void k_attn(const f16* __restrict__ Qh,
        const f16* __restrict__ Kh, const f16* __restrict__ Vt,
        const float* __restrict__ qn, const float* __restrict__ kn,
        const float* __restrict__ alpha, f16* __restrict__ AO) {
    const int tid = threadIdx.x;
    const int wv = tid >> 6, ln = tid & 63;
    const int task = blockIdx.x * 4 + wv;
    const int bh = task & (BH - 1);
    const int qb = (SS / 32 - 1) - (task >> 5);     // longest first
    const int lq = ln & 31, hi = ln >> 5;
    const int q0 = qb * 32;
    const float scl = powf(8.0f / logf(65.0f), alpha[0]);
    const f16* __restrict__ Qp = Qh + (size_t)bh * SS * HDD;
    const f16* __restrict__ Kp = Kh + (size_t)bh * SS * HDD;
    const f16* __restrict__ Vp = Vt + (size_t)bh * HDD * SS;
    const float* __restrict__ knp = kn + (size_t)bh * SS;

    // Q B-fragments (col=q=lq, 8 consecutive d per half): 4 d-tiles of 16
    f16x8 qf[4];
#pragma unroll
    for (int dt = 0; dt < 4; ++dt)
        qf[dt] = *(const f16x8*)&Qp[(size_t)(q0 + lq) * HDD + dt * 16 + hi * 8];
    const float qnl = qn[(size_t)bh * SS + q0 + lq] + 1e-5f;  // eps folded in

    float m_ = -INFINITY, l_ = 0.f;
    f32x16 o0 = {}, o1 = {};
    const int ktd = qb >> 1;
    const int qg = q0 + lq;

    auto body = [&](int kb, bool tri0, bool tri1, bool use1) {
        f32x16 s0 = {}, s1 = {};
#pragma unroll
        for (int dt = 0; dt < 4; ++dt) {
            f16x8 kf = *(const f16x8*)&Kp[(size_t)(kb + lq) * HDD + dt * 16 + hi * 8];
            s0 = MFMA32(kf, qf[dt], s0);
        }
        if (use1) {
#pragma unroll
            for (int dt = 0; dt < 4; ++dt) {
                f16x8 kf = *(const f16x8*)&Kp[(size_t)(kb + 32 + lq) * HDD + dt * 16 + hi * 8];
                s1 = MFMA32(kf, qf[dt], s1);
            }
        }
        float4 kn0[4], kn1[4];
#pragma unroll
        for (int g = 0; g < 4; ++g)
            kn0[g] = *(const float4*)&knp[kb + 8 * g + 4 * hi];
        if (use1) {
#pragma unroll
            for (int g = 0; g < 4; ++g)
                kn1[g] = *(const float4*)&knp[kb + 32 + 8 * g + 4 * hi];
        }
#pragma unroll
        for (int r = 0; r < 16; ++r) {
            const int koff = (r & 3) + 8 * (r >> 2) + 4 * hi;
            float qk = s0[r];
            float d2 = qnl + kn0[r >> 2][r & 3] - 2.f * qk;
            float sc = qk * qk * scl * __builtin_amdgcn_rcpf(d2);
            if (tri0 && (kb + koff > qg)) sc = -3.0e38f;
            s0[r] = sc;
            if (use1) {
                float qk1 = s1[r];
                float d21 = qnl + kn1[r >> 2][r & 3] - 2.f * qk1;
                float sc1 = qk1 * qk1 * scl * __builtin_amdgcn_rcpf(d21);
                if (tri1 && (kb + 32 + koff > qg)) sc1 = -3.0e38f;
                s1[r] = sc1;
            }
        }
        float mx = -3.0e38f;
#pragma unroll
        for (int r = 0; r < 16; ++r) mx = fmaxf(mx, s0[r]);
        if (use1) {
#pragma unroll
            for (int r = 0; r < 16; ++r) mx = fmaxf(mx, s1[r]);
        }
        mx = fmaxf(mx, __shfl_xor(mx, 32));
        if (__any(mx > m_)) {            // exact defer: skip is a no-op case
            float mnew = fmaxf(m_, mx);
            float corr = __expf(m_ - mnew);
            m_ = mnew;
            l_ *= corr;
#pragma unroll
            for (int r = 0; r < 16; ++r) {
                float cr = __shfl(corr, (r & 3) + 8 * (r >> 2) + 4 * hi);
                o0[r] *= cr; o1[r] *= cr;
            }
        }
        float ps = 0.f;
#pragma unroll
        for (int r = 0; r < 16; ++r) {
            float p = __expf(s0[r] - m_); s0[r] = p; ps += p;
        }
        if (use1) {
#pragma unroll
            for (int r = 0; r < 16; ++r) {
                float p = __expf(s1[r] - m_); s1[r] = p; ps += p;
            }
        }
        ps += __shfl_xor(ps, 32);
        l_ += ps;
        f16x8 pa0 = pack8(s0[0], s0[1], s0[2], s0[3], s0[4], s0[5], s0[6], s0[7], hi);
        f16x8 pa1 = pack8(s0[8], s0[9], s0[10], s0[11], s0[12], s0[13], s0[14], s0[15], hi);
#pragma unroll
        for (int k16 = 0; k16 < 2; ++k16) {
            f16x8 pa = k16 ? pa1 : pa0;
            f16x8 vf0 = *(const f16x8*)&Vp[(size_t)lq * SS + kb + k16 * 16 + hi * 8];
            f16x8 vf1 = *(const f16x8*)&Vp[(size_t)(32 + lq) * SS + kb + k16 * 16 + hi * 8];
            o0 = MFMA32(pa, vf0, o0);
            o1 = MFMA32(pa, vf1, o1);
        }
        if (use1) {
            f16x8 pb0 = pack8(s1[0], s1[1], s1[2], s1[3], s1[4], s1[5], s1[6], s1[7], hi);
            f16x8 pb1 = pack8(s1[8], s1[9], s1[10], s1[11], s1[12], s1[13], s1[14], s1[15], hi);
#pragma unroll
            for (int k16 = 0; k16 < 2; ++k16) {
                f16x8 pb = k16 ? pb1 : pb0;
                f16x8 vf0 = *(const f16x8*)&Vp[(size_t)lq * SS + kb + 32 + k16 * 16 + hi * 8];
                f16x8 vf1 = *(const f16x8*)&Vp[(size_t)(32 + lq) * SS + kb + 32 + k16 * 16 + hi * 8];
                o0 = MFMA32(pb, vf0, o0);
                o1 = MFMA32(pb, vf1, o1);
            }
        }
    };

    for (int kt = 0; kt < ktd; ++kt) body(kt * 64, false, false, true);
    {   // diagonal tile
        const bool odd = (qb & 1) != 0;
        body(ktd * 64, !odd, odd, odd);
    }

    float li = 1.0f / l_;
#pragma unroll
    for (int r = 0; r < 16; ++r) {
        int qlo = (r & 3) + 8 * (r >> 2) + 4 * hi;
        float lir = __shfl(li, qlo);
        size_t row = (size_t)bh * SS + q0 + qlo;
        AO[row * HDD + lq] = (f16)(o0[r] * lir);
        AO[row * HDD + 32 + lq] = (f16)(o1[r] * lir);
    }
}

// ---------------------------------------------------------------------------
// out = AO(gathered to (b,s,h*hd)) @ Wo  (fp16 MFMA, fp32 out)
// ---------------------------------------------------------------------------
__global__ __launch_bounds__(256) void k_proj(const f16* __restrict__ AO,
        const f16* __restrict__ Wot, float* __restrict__ out) {
    const int m0 = blockIdx.x * 128;
    const int n0 = blockIdx.y * 128;
    __shared__ f16 As[128 * 32];
    __shared__ f16 Bs[128 * 32];
    const int tid = threadIdx.x;
    const int wv = tid >> 6, ln = tid & 63;
    const int wm = wv >> 1, wn = wv & 1;
    const int lg = ln >> 4, lr = ln & 15;
    f32x4 acc[4][4] = {};
    for (int k0 = 0; k0 < DD; k0 += 32) {
        __syncthreads();
#pragma unroll
        for (int u = 0; u < 2; ++u) {
            int e = u * 2048 + wv * 512 + ln * 8;
            int r = e >> 5, c = e & 31;
            int gm = m0 + r, b = gm >> 11, s = gm & (SS - 1);
            int k = k0 + c, h = k >> 6, d = k & 63;
            gload16(&AO[(((size_t)b * HH + h) * SS + s) * HDD + d], &As[e]);
            gload16(&Wot[(size_t)(n0 + r) * DD + k0 + c], &Bs[e]);
        }
        __syncthreads();
        f16x8 af[4], bf[4];
#pragma unroll
        for (int mt = 0; mt < 4; ++mt)
            af[mt] = *(const f16x8*)&As[(wm * 64 + mt * 16 + lr) * 32 + lg * 8];
#pragma unroll
        for (int nt = 0; nt < 4; ++nt)
            bf[nt] = *(const f16x8*)&Bs[(wn * 64 + nt * 16 + lr) * 32 + lg * 8];
#pragma unroll
        for (int mt = 0; mt < 4; ++mt)
#pragma unroll
            for (int nt = 0; nt < 4; ++nt)
                acc[mt][nt] = MFMA(af[mt], bf[nt], acc[mt][nt]);
    }
#pragma unroll
    for (int mt = 0; mt < 4; ++mt)
#pragma unroll
        for (int reg = 0; reg < 4; ++reg) {
            int gr = m0 + wm * 64 + mt * 16 + lg * 4 + reg;
#pragma unroll
            for (int nt = 0; nt < 4; ++nt) {
                int gc = n0 + wn * 64 + nt * 16 + lr;
                out[(size_t)gr * DD + gc] = acc[mt][nt][reg];
            }
        }
}

extern "C" void kernel_launch(void* const* d_in, const int* in_sizes, int n_in,
                              void* d_out, int out_size, void* d_ws, size_t ws_size,
                              hipStream_t stream) {
    const float* x     = (const float*)d_in[0];
    const float* Wq    = (const float*)d_in[1];
    const float* Wk    = (const float*)d_in[2];
    const float* Wv    = (const float*)d_in[3];
    const float* Wo    = (const float*)d_in[4];
    const float* alpha = (const float*)d_in[5];
    float* out = (float*)d_out;

    float* cosT = (float*)d_ws;
    float* sinT = cosT + SS * 32;
    float* qn   = sinT + SS * 32;
    float* kn   = qn + (size_t)BH * SS;
    f16* xb     = (f16*)(kn + (size_t)BH * SS);
    f16* WtAll  = xb + (size_t)MM * DD;
    f16* Qh     = WtAll + (size_t)4 * DD * DD;
    f16* Kh     = Qh + (size_t)MM * DD;
    f16* Vh     = Kh + (size_t)MM * DD;
    f16* Vt     = Vh + (size_t)MM * DD;
    f16* AO     = Vt + (size_t)MM * DD;
    f16* Wot    = WtAll + (size_t)3 * DD * DD;

    hipLaunchKernelGGL(k_rope_table, dim3(SS * 32 / 256), dim3(256), 0, stream,
                       cosT, sinT);
    hipLaunchKernelGGL(k_cast_x, dim3(MM * DD / (256 * 8)), dim3(256), 0, stream,
                       x, xb);
    hipLaunchKernelGGL(k_wcast, dim3(16, 16, 4), dim3(256), 0, stream,
                       Wq, Wk, Wv, Wo, WtAll);
    hipLaunchKernelGGL(k_qkv, dim3(MM / 128, DD / 128, 3), dim3(256), 0, stream,
                       xb, WtAll, cosT, sinT, Qh, Kh, Vh, qn, kn);
    hipLaunchKernelGGL(k_vt, dim3(SS / 64, BH), dim3(256), 0, stream, Vh, Vt);
    hipLaunchKernelGGL(k_attn, dim3((SS / 32) * BH / 4), dim3(256), 0, stream,
                       Qh, Kh, Vt, qn, kn, alpha, AO);
    hipLaunchKernelGGL(k_proj, dim3(MM / 128, DD / 128), dim3(256), 0, stream,
                       AO, Wot, out);
}

// Round 5
// 259.379 us; speedup vs baseline: 4.1647x; 1.1205x over previous
//
#include <hip/hip_runtime.h>
#include <cmath>

#define BB 2
#define SS 2048
#define DD 1024
#define HH 16
#define HDD 64
#define MM (BB * SS)
#define BH (BB * HH)

typedef _Float16 f16;
typedef _Float16 f16x2 __attribute__((ext_vector_type(2)));
typedef _Float16 f16x4 __attribute__((ext_vector_type(4)));
typedef _Float16 f16x8 __attribute__((ext_vector_type(8)));
typedef float f32x4 __attribute__((ext_vector_type(4)));
typedef float f32x16 __attribute__((ext_vector_type(16)));
typedef unsigned int u32x4 __attribute__((ext_vector_type(4)));

#define MFMA(A, B, C) __builtin_amdgcn_mfma_f32_16x16x32_f16(A, B, C, 0, 0, 0)
#define MFMA32(A, B, C) __builtin_amdgcn_mfma_f32_32x32x16_f16(A, B, C, 0, 0, 0)

__device__ __forceinline__ void gload16(const void* g, void* l) {
    __builtin_amdgcn_global_load_lds(
        (const __attribute__((address_space(1))) void*)g,
        (__attribute__((address_space(3))) void*)l, 16, 0, 0);
}

__device__ __forceinline__ unsigned pk(float a, float b) {
    auto h = __builtin_amdgcn_cvt_pkrtz(a, b);   // __fp16 ext_vector(2)
    return __builtin_bit_cast(unsigned, h);
}

// Build the PV A-fragment (16 consecutive k) from 8 per-lane P values whose
// k-pattern is (r&3)+8*(r>>2)+4*hi. Half-exchange via shfl_xor(32)+select.
__device__ __forceinline__ f16x8 pack8(float p0, float p1, float p2, float p3,
                                       float p4, float p5, float p6, float p7,
                                       int hi) {
    unsigned wa = pk(p0, p1), wa2 = pk(p2, p3);
    unsigned wb = pk(p4, p5), wb2 = pk(p6, p7);
    unsigned xa = __shfl_xor(wa, 32), xa2 = __shfl_xor(wa2, 32);
    unsigned xb = __shfl_xor(wb, 32), xb2 = __shfl_xor(wb2, 32);
    unsigned w0 = hi ? xb : wa;
    unsigned w1 = hi ? xb2 : wa2;
    unsigned w2 = hi ? wb : xa;
    unsigned w3 = hi ? wb2 : xa2;
    u32x4 w = {w0, w1, w2, w3};
    return __builtin_bit_cast(f16x8, w);
}

// ---------------------------------------------------------------------------
// RoPE cos/sin table (fp64 trig to match numpy).
// ---------------------------------------------------------------------------
__global__ __launch_bounds__(256) void k_rope_table(float* __restrict__ cosT,
                                                    float* __restrict__ sinT) {
    int idx = blockIdx.x * 256 + threadIdx.x;
    int s = idx >> 5, j = idx & 31;
    double inv = pow(10000.0, -(double)(2 * j) / 64.0);
    double ang = (double)s * inv;
    cosT[idx] = (float)cos(ang);
    sinT[idx] = (float)sin(ang);
}

// ---------------------------------------------------------------------------
// x (fp32, M x D) -> xb (fp16, same layout)
// ---------------------------------------------------------------------------
__global__ __launch_bounds__(256) void k_cast_x(const float* __restrict__ x,
                                                f16* __restrict__ xb) {
    int i = (blockIdx.x * 256 + threadIdx.x) * 8;
    float4 a = *(const float4*)&x[i];
    float4 b = *(const float4*)&x[i + 4];
    f16x8 o = {(f16)a.x, (f16)a.y, (f16)a.z, (f16)a.w,
               (f16)b.x, (f16)b.y, (f16)b.z, (f16)b.w};
    *(f16x8*)&xb[i] = o;
}

// ---------------------------------------------------------------------------
// W (fp32, K x N) -> Wt (fp16, N x K)  for Wq,Wk,Wv,Wo (z = 0..3)
// ---------------------------------------------------------------------------
__global__ __launch_bounds__(256) void k_wcast(const float* __restrict__ Wq,
        const float* __restrict__ Wk, const float* __restrict__ Wv,
        const float* __restrict__ Wo, f16* __restrict__ WtAll) {
    const int z = blockIdx.z;
    const float* __restrict__ src = (z == 0) ? Wq : (z == 1) ? Wk
                                   : (z == 2) ? Wv : Wo;
    f16* __restrict__ dst = WtAll + (size_t)z * DD * DD;
    const int kk0 = blockIdx.x * 64, nn0 = blockIdx.y * 64;
    __shared__ float t[64][65];
    const int tid = threadIdx.x;
    const int rr = tid >> 4, c4 = (tid & 15) * 4;
#pragma unroll
    for (int p = 0; p < 4; ++p) {
        float4 v = *(const float4*)&src[(size_t)(kk0 + p * 16 + rr) * DD + nn0 + c4];
        t[p * 16 + rr][c4 + 0] = v.x; t[p * 16 + rr][c4 + 1] = v.y;
        t[p * 16 + rr][c4 + 2] = v.z; t[p * 16 + rr][c4 + 3] = v.w;
    }
    __syncthreads();
#pragma unroll
    for (int p = 0; p < 4; ++p) {
        int n = p * 16 + rr;
        f16x4 o = {(f16)t[c4 + 0][n], (f16)t[c4 + 1][n],
                   (f16)t[c4 + 2][n], (f16)t[c4 + 3][n]};
        *(f16x4*)&dst[(size_t)(nn0 + n) * DD + kk0 + c4] = o;
    }
}

// ---------------------------------------------------------------------------
// QKV GEMM (fp16 MFMA, 128x128 tile, BK=32, global_load_lds staging).
// Epilogue: RoPE (Q,K) + store (B,H,S,HD); K row norms (fp32 -> f16 array).
// ---------------------------------------------------------------------------
__global__ __launch_bounds__(256) void k_qkv(const f16* __restrict__ xb,
        const f16* __restrict__ WtAll,
        const float* __restrict__ cosT, const float* __restrict__ sinT,
        f16* __restrict__ Qh, f16* __restrict__ Kh, f16* __restrict__ Vh,
        f16* __restrict__ knh) {
    const int z = blockIdx.z;
    const f16* __restrict__ Wt = WtAll + (size_t)z * DD * DD;
    f16* __restrict__ dst = (z == 0) ? Qh : (z == 1) ? Kh : Vh;
    const int m0 = blockIdx.x * 128;
    const int n0 = blockIdx.y * 128;
    __shared__ f16 As[128 * 32];
    __shared__ f16 Bs[128 * 32];
    const int tid = threadIdx.x;
    const int wv = tid >> 6, ln = tid & 63;
    const int wm = wv >> 1, wn = wv & 1;
    const int lg = ln >> 4, lr = ln & 15;
    f32x4 acc[4][4] = {};
    for (int k0 = 0; k0 < DD; k0 += 32) {
        __syncthreads();
#pragma unroll
        for (int u = 0; u < 2; ++u) {
            int e = u * 2048 + wv * 512 + ln * 8;
            int r = e >> 5, c = e & 31;
            gload16(&xb[(size_t)(m0 + r) * DD + k0 + c], &As[e]);
            gload16(&Wt[(size_t)(n0 + r) * DD + k0 + c], &Bs[e]);
        }
        __syncthreads();
        f16x8 af[4], bf[4];
#pragma unroll
        for (int mt = 0; mt < 4; ++mt)
            af[mt] = *(const f16x8*)&As[(wm * 64 + mt * 16 + lr) * 32 + lg * 8];
#pragma unroll
        for (int nt = 0; nt < 4; ++nt)
            bf[nt] = *(const f16x8*)&Bs[(wn * 64 + nt * 16 + lr) * 32 + lg * 8];
#pragma unroll
        for (int mt = 0; mt < 4; ++mt)
#pragma unroll
            for (int nt = 0; nt < 4; ++nt)
                acc[mt][nt] = MFMA(af[mt], bf[nt], acc[mt][nt]);
    }
    const bool isv = (z == 2);
#pragma unroll
    for (int mt = 0; mt < 4; ++mt) {
        float nsum[4] = {0.f, 0.f, 0.f, 0.f};
#pragma unroll
        for (int reg = 0; reg < 4; ++reg) {
            int gr = m0 + wm * 64 + mt * 16 + lg * 4 + reg;
            int b = gr >> 11, s = gr & (SS - 1);
#pragma unroll
            for (int nt = 0; nt < 4; ++nt) {
                int gc = n0 + wn * 64 + nt * 16 + lr;
                int h = gc >> 6, d = gc & 63;
                float v = acc[mt][nt][reg];
                if (!isv) {
                    float p = __shfl_xor(v, 1);
                    int pr = d >> 1;
                    float cz = cosT[s * 32 + pr], sz = sinT[s * 32 + pr];
                    if ((lr & 1) == 0) {
                        float oe = v * cz - p * sz;
                        float oo = v * sz + p * cz;
                        f16x2 st; st[0] = (f16)oe; st[1] = (f16)oo;
                        *(f16x2*)&dst[(((size_t)b * HH + h) * SS + s) * HDD + d] = st;
                        if (z == 1) nsum[reg] += oe * oe + oo * oo;
                    }
                } else {
                    dst[(((size_t)b * HH + h) * SS + s) * HDD + d] = (f16)v;
                }
            }
        }
        if (z == 1) {
#pragma unroll
            for (int reg = 0; reg < 4; ++reg) {
                float ns = nsum[reg];
                ns += __shfl_xor(ns, 1); ns += __shfl_xor(ns, 2);
                ns += __shfl_xor(ns, 4); ns += __shfl_xor(ns, 8);
                if (lr == 0) {
                    int gr = m0 + wm * 64 + mt * 16 + lg * 4 + reg;
                    int b = gr >> 11, s = gr & (SS - 1);
                    int h = (n0 + wn * 64) >> 6;
                    knh[((size_t)b * HH + h) * SS + s] = (f16)ns;
                }
            }
        }
    }
}

// ---------------------------------------------------------------------------
// Vh (B,H,S,HD) -> Vt (B,H,HD,S)
// ---------------------------------------------------------------------------
__global__ __launch_bounds__(256) void k_vt(const f16* __restrict__ Vh,
                                            f16* __restrict__ Vt) {
    const int s0 = blockIdx.x * 64;
    const int bh = blockIdx.y;
    __shared__ f16 t[64][80];
    const int tid = threadIdx.x;
    const int sr = tid >> 3, d0 = (tid & 7) * 8;
#pragma unroll
    for (int p = 0; p < 2; ++p) {
        f16x8 v = *(const f16x8*)&Vh[((size_t)bh * SS + s0 + p * 32 + sr) * HDD + d0];
#pragma unroll
        for (int j = 0; j < 8; ++j) t[d0 + j][p * 32 + sr] = v[j];
    }
    __syncthreads();
    const int dr = tid >> 3, s4 = (tid & 7) * 8;
#pragma unroll
    for (int p = 0; p < 2; ++p) {
        f16x8 o = *(const f16x8*)&t[p * 32 + dr][s4];
        *(f16x8*)&Vt[((size_t)bh * HDD + p * 32 + dr) * SS + s0 + s4] = o;
    }
}

// ---------------------------------------------------------------------------
// Yat attention, swapped-QK^T 32x32x16, 4-way k-split per block + LDS merge.
// Block = one 32-row q-tile of one (b,h); wave w handles 32-k tiles
// kt ≡ w (mod 4); diagonal tile by wave (qb&3). Online softmax per wave
// (lane-local rows, defer-rescale THR=8); merge of 4 flash states in LDS.
// ---------------------------------------------------------------------------
__global__ __launch_bounds__(256, 4) void k_attn(const f16* __restrict__ Qh,
        const f16* __restrict__ Kh, const f16* __restrict__ Vt,
        const f16* __restrict__ knh,
        const float* __restrict__ alpha, f16* __restrict__ AO) {
    const int tid = threadIdx.x;
    const int wv = tid >> 6, ln = tid & 63;
    const int lq = ln & 31, hi = ln >> 5;
    const int blk = blockIdx.x;
    const int bh = blk & (BH - 1);
    const int qb = (SS / 32 - 1) - (blk >> 5);     // longest first
    const int q0 = qb * 32;
    const float scl = powf(8.0f / logf(65.0f), alpha[0]);
    const f16* __restrict__ Qp = Qh + (size_t)bh * SS * HDD;
    const f16* __restrict__ Kp = Kh + (size_t)bh * SS * HDD;
    const f16* __restrict__ Vp = Vt + (size_t)bh * HDD * SS;
    const f16* __restrict__ knp = knh + (size_t)bh * SS;

    __shared__ float oL[4][32][68];
    __shared__ float mlL[4][2][32];

    f16x8 qf[4];
#pragma unroll
    for (int dt = 0; dt < 4; ++dt)
        qf[dt] = *(const f16x8*)&Qp[(size_t)(q0 + lq) * HDD + dt * 16 + hi * 8];
    float qn = 0.f;
#pragma unroll
    for (int dt = 0; dt < 4; ++dt)
#pragma unroll
        for (int j = 0; j < 8; ++j) {
            float v = (float)qf[dt][j];
            qn = fmaf(v, v, qn);
        }
    qn += __shfl_xor(qn, 32);
    const float qnl = qn + 1e-5f;                  // eps folded in

    float m_ = -INFINITY, l_ = 0.f;
    f32x16 o0 = {}, o1 = {};
    f16x8 kf[4];

    if (wv < qb) {
        int kb = wv * 32;
#pragma unroll
        for (int dt = 0; dt < 4; ++dt)
            kf[dt] = *(const f16x8*)&Kp[(size_t)(kb + lq) * HDD + dt * 16 + hi * 8];
    }

    auto tile = [&](int kb, bool diag, bool pre, int kbn) {
        // V + kn issued at top (in flight across QK^T + softmax)
        f16x8 vf0 = *(const f16x8*)&Vp[(size_t)lq * SS + kb + hi * 8];
        f16x8 vf1 = *(const f16x8*)&Vp[(size_t)lq * SS + kb + 16 + hi * 8];
        f16x8 vf2 = *(const f16x8*)&Vp[(size_t)(32 + lq) * SS + kb + hi * 8];
        f16x8 vf3 = *(const f16x8*)&Vp[(size_t)(32 + lq) * SS + kb + 16 + hi * 8];
        f16x4 knv[4];
#pragma unroll
        for (int g = 0; g < 4; ++g)
            knv[g] = *(const f16x4*)&knp[kb + 8 * g + 4 * hi];
        f32x16 s = {};
#pragma unroll
        for (int dt = 0; dt < 4; ++dt) s = MFMA32(kf[dt], qf[dt], s);
        if (pre) {   // next-tile K into same regs (in flight across softmax+PV)
#pragma unroll
            for (int dt = 0; dt < 4; ++dt)
                kf[dt] = *(const f16x8*)&Kp[(size_t)(kbn + lq) * HDD + dt * 16 + hi * 8];
        }
#pragma unroll
        for (int r = 0; r < 16; ++r) {
            const int koff = (r & 3) + 8 * (r >> 2) + 4 * hi;
            float qk = s[r];
            float kv = (float)knv[r >> 2][r & 3];
            float d2 = qnl + kv - 2.0f * qk;
            float sc = qk * qk * scl * __builtin_amdgcn_rcpf(d2);
            if (diag && koff > lq) sc = -3.0e38f;
            s[r] = sc;
        }
        float mx = -3.0e38f;
#pragma unroll
        for (int r = 0; r < 16; ++r) mx = fmaxf(mx, s[r]);
        mx = fmaxf(mx, __shfl_xor(mx, 32));
        if (__any(mx > m_ + 8.0f)) {               // T13 defer-rescale
            float mnew = fmaxf(m_, mx);
            float corr = __expf(m_ - mnew);
            m_ = mnew; l_ *= corr;
#pragma unroll
            for (int r = 0; r < 16; ++r) {
                float cr = __shfl(corr, (r & 3) + 8 * (r >> 2) + 4 * hi);
                o0[r] *= cr; o1[r] *= cr;
            }
        }
        float ps = 0.f;
#pragma unroll
        for (int r = 0; r < 16; ++r) {
            float p = __expf(s[r] - m_); s[r] = p; ps += p;
        }
        ps += __shfl_xor(ps, 32);
        l_ += ps;
        f16x8 pa0 = pack8(s[0], s[1], s[2], s[3], s[4], s[5], s[6], s[7], hi);
        f16x8 pa1 = pack8(s[8], s[9], s[10], s[11], s[12], s[13], s[14], s[15], hi);
        o0 = MFMA32(pa0, vf0, o0);
        o0 = MFMA32(pa1, vf1, o0);
        o1 = MFMA32(pa0, vf2, o1);
        o1 = MFMA32(pa1, vf3, o1);
    };

    for (int kt = wv; kt < qb; kt += 4) {
        const bool pre = (kt + 4 < qb);
        tile(kt * 32, false, pre, pre ? (kt + 4) * 32 : 0);
    }
    if ((qb & 3) == wv) {                          // diagonal tile
        int kb = qb * 32;
#pragma unroll
        for (int dt = 0; dt < 4; ++dt)
            kf[dt] = *(const f16x8*)&Kp[(size_t)(kb + lq) * HDD + dt * 16 + hi * 8];
        tile(kb, true, false, 0);
    }

    // ---- merge 4 flash states ----
#pragma unroll
    for (int r = 0; r < 16; ++r) {
        int q = (r & 3) + 8 * (r >> 2) + 4 * hi;
        oL[wv][q][lq] = o0[r];
        oL[wv][q][32 + lq] = o1[r];
    }
    if (hi == 0) { mlL[wv][0][lq] = m_; mlL[wv][1][lq] = l_; }
    __syncthreads();
    {
        const int q = tid >> 3, d8 = (tid & 7) * 8;
        float mv[4], lv[4];
#pragma unroll
        for (int i = 0; i < 4; ++i) { mv[i] = mlL[i][0][q]; lv[i] = mlL[i][1][q]; }
        float M = fmaxf(fmaxf(mv[0], mv[1]), fmaxf(mv[2], mv[3]));
        float fac[4], L = 0.f;
#pragma unroll
        for (int i = 0; i < 4; ++i) {
            fac[i] = __expf(mv[i] - M);
            L = fmaf(lv[i], fac[i], L);
        }
        float rL = 1.0f / L;
        float acc[8] = {};
#pragma unroll
        for (int i = 0; i < 4; ++i) {
            float4 a = *(const float4*)&oL[i][q][d8];
            float4 b = *(const float4*)&oL[i][q][d8 + 4];
            acc[0] = fmaf(a.x, fac[i], acc[0]);
            acc[1] = fmaf(a.y, fac[i], acc[1]);
            acc[2] = fmaf(a.z, fac[i], acc[2]);
            acc[3] = fmaf(a.w, fac[i], acc[3]);
            acc[4] = fmaf(b.x, fac[i], acc[4]);
            acc[5] = fmaf(b.y, fac[i], acc[5]);
            acc[6] = fmaf(b.z, fac[i], acc[6]);
            acc[7] = fmaf(b.w, fac[i], acc[7]);
        }
        f16x8 st;
#pragma unroll
        for (int j = 0; j < 8; ++j) st[j] = (f16)(acc[j] * rL);
        *(f16x8*)&AO[((size_t)bh * SS + q0 + q) * HDD + d8] = st;
    }
}

// ---------------------------------------------------------------------------
// out = AO(gathered to (b,s,h*hd)) @ Wo  (fp16 MFMA, fp32 out)
// ---------------------------------------------------------------------------
__global__ __launch_bounds__(256) void k_proj(const f16* __restrict__ AO,
        const f16* __restrict__ Wot, float* __restrict__ out) {
    const int m0 = blockIdx.x * 128;
    const int n0 = blockIdx.y * 128;
    __shared__ f16 As[128 * 32];
    __shared__ f16 Bs[128 * 32];
    const int tid = threadIdx.x;
    const int wv = tid >> 6, ln = tid & 63;
    const int wm = wv >> 1, wn = wv & 1;
    const int lg = ln >> 4, lr = ln & 15;
    f32x4 acc[4][4] = {};
    for (int k0 = 0; k0 < DD; k0 += 32) {
        __syncthreads();
#pragma unroll
        for (int u = 0; u < 2; ++u) {
            int e = u * 2048 + wv * 512 + ln * 8;
            int r = e >> 5, c = e & 31;
            int gm = m0 + r, b = gm >> 11, s = gm & (SS - 1);
            int k = k0 + c, h = k >> 6, d = k & 63;
            gload16(&AO[(((size_t)b * HH + h) * SS + s) * HDD + d], &As[e]);
            gload16(&Wot[(size_t)(n0 + r) * DD + k0 + c], &Bs[e]);
        }
        __syncthreads();
        f16x8 af[4], bf[4];
#pragma unroll
        for (int mt = 0; mt < 4; ++mt)
            af[mt] = *(const f16x8*)&As[(wm * 64 + mt * 16 + lr) * 32 + lg * 8];
#pragma unroll
        for (int nt = 0; nt < 4; ++nt)
            bf[nt] = *(const f16x8*)&Bs[(wn * 64 + nt * 16 + lr) * 32 + lg * 8];
#pragma unroll
        for (int mt = 0; mt < 4; ++mt)
#pragma unroll
            for (int nt = 0; nt < 4; ++nt)
                acc[mt][nt] = MFMA(af[mt], bf[nt], acc[mt][nt]);
    }
#pragma unroll
    for (int mt = 0; mt < 4; ++mt)
#pragma unroll
        for (int reg = 0; reg < 4; ++reg) {
            int gr = m0 + wm * 64 + mt * 16 + lg * 4 + reg;
#pragma unroll
            for (int nt = 0; nt < 4; ++nt) {
                int gc = n0 + wn * 64 + nt * 16 + lr;
                out[(size_t)gr * DD + gc] = acc[mt][nt][reg];
            }
        }
}

extern "C" void kernel_launch(void* const* d_in, const int* in_sizes, int n_in,
                              void* d_out, int out_size, void* d_ws, size_t ws_size,
                              hipStream_t stream) {
    const float* x     = (const float*)d_in[0];
    const float* Wq    = (const float*)d_in[1];
    const float* Wk    = (const float*)d_in[2];
    const float* Wv    = (const float*)d_in[3];
    const float* Wo    = (const float*)d_in[4];
    const float* alpha = (const float*)d_in[5];
    float* out = (float*)d_out;

    float* cosT = (float*)d_ws;
    float* sinT = cosT + SS * 32;
    f16* knh    = (f16*)(sinT + SS * 32);
    f16* xb     = knh + (size_t)BH * SS;
    f16* WtAll  = xb + (size_t)MM * DD;
    f16* Qh     = WtAll + (size_t)4 * DD * DD;
    f16* Kh     = Qh + (size_t)MM * DD;
    f16* Vh     = Kh + (size_t)MM * DD;
    f16* Vt     = Vh + (size_t)MM * DD;
    f16* AO     = Vt + (size_t)MM * DD;
    f16* Wot    = WtAll + (size_t)3 * DD * DD;

    hipLaunchKernelGGL(k_rope_table, dim3(SS * 32 / 256), dim3(256), 0, stream,
                       cosT, sinT);
    hipLaunchKernelGGL(k_cast_x, dim3(MM * DD / (256 * 8)), dim3(256), 0, stream,
                       x, xb);
    hipLaunchKernelGGL(k_wcast, dim3(16, 16, 4), dim3(256), 0, stream,
                       Wq, Wk, Wv, Wo, WtAll);
    hipLaunchKernelGGL(k_qkv, dim3(MM / 128, DD / 128, 3), dim3(256), 0, stream,
                       xb, WtAll, cosT, sinT, Qh, Kh, Vh, knh);
    hipLaunchKernelGGL(k_vt, dim3(SS / 64, BH), dim3(256), 0, stream, Vh, Vt);
    hipLaunchKernelGGL(k_attn, dim3((SS / 32) * BH), dim3(256), 0, stream,
                       Qh, Kh, Vt, knh, alpha, AO);
    hipLaunchKernelGGL(k_proj, dim3(MM / 128, DD / 128), dim3(256), 0, stream,
                       AO, Wot, out);
}